// Round 10
// baseline (401.678 us; speedup 1.0000x reference)
//
#include <hip/hip_runtime.h>

// GNN: 2x GCNConv(relu) + mean-pool + MLP head.
// Sizes fixed: N=50000, E=800000, F_IN=256, H=64, NC=4, NG=64.
//
// R9: hs/hb bf16, f32 accumulate. R11: dual-edge packed gather.
// R15: decomposition: pool+head1+head2 = 2.6us, dispatch overhead ~0.
// R16: gemm2 fused into agg1 (free) -> kept.
// R17/R18/R19: agg rewrites converge at 42.5us, FETCH 33MB invariant
//      -> random-line TCC-fill wall (2 lines/edge, bf16-irreducible).
// R20: pure-bf16 gemm1 (absmax unchanged — lo-planes irrelevant).
// R21: barrier-free streaming gemm1: 45 -> ~18us (occ-starved barrier
//      K-loop was the cost). Total 256.9 -> 235.6.
// R22 (this round): passA/passB (~40us each: barrier-heavy LDS-scan
//      bucket sort) replaced by 3 trivially-parallel kernels:
//      k_deg (800k global atomicAdd), k_scan (one 1024-thr block:
//      serial+LDS scan -> csr_off, dinv), k_scatter (atomicSub on deg
//      as cursor, scattered L2-resident writes). Edge order within a
//      node becomes arbitrary — segment sum is order-independent.

#define TPB 256

typedef unsigned short bfu;
typedef __attribute__((ext_vector_type(8))) short s16x8;
typedef __attribute__((ext_vector_type(4))) float f32x4;

__device__ __forceinline__ float bf2f(bfu u) {
    union { unsigned u32; float f; } c; c.u32 = ((unsigned)u) << 16; return c.f;
}
__device__ __forceinline__ bfu f2bf(float f) {
    union { float f; unsigned u; } c; c.f = f;
    unsigned r = 0x7FFFu + ((c.u >> 16) & 1u);     // round-to-nearest-even
    return (bfu)((c.u + r) >> 16);
}
__device__ __forceinline__ float blo(unsigned w) {
    union { unsigned u32; float f; } c; c.u32 = w << 16; return c.f;
}
__device__ __forceinline__ float bhi(unsigned w) {
    union { unsigned u32; float f; } c; c.u32 = w & 0xFFFF0000u; return c.f;
}

// ---------------- CSR build (R22): histogram / scan / scatter ----------------

__global__ __launch_bounds__(TPB) void k_deg(const int* __restrict__ dstv, int E,
                                             int* __restrict__ deg) {
    int i = blockIdx.x * TPB + threadIdx.x;
    if (i < E) atomicAdd(&deg[dstv[i]], 1);
}

// One block, 1024 threads. Thread t owns rows [t*C, t*C+C).
__global__ __launch_bounds__(1024) void k_scan(const int* __restrict__ deg, int n,
                                               int* __restrict__ csr_off,
                                               float* __restrict__ dinv) {
    __shared__ int part[1024];
    int t = threadIdx.x;
    int C = (n + 1023) >> 10;
    int i0 = t * C;
    int s = 0;
    for (int j = 0; j < C; j++) {
        int i = i0 + j;
        if (i < n) s += deg[i];
    }
    part[t] = s;
    __syncthreads();
    for (int off = 1; off < 1024; off <<= 1) {
        int u = (t >= off) ? part[t - off] : 0;
        __syncthreads();
        part[t] += u;
        __syncthreads();
    }
    int run = part[t] - s;   // exclusive prefix
    for (int j = 0; j < C; j++) {
        int i = i0 + j;
        if (i < n) {
            int dg = deg[i];
            csr_off[i] = run;
            dinv[i] = rsqrtf((float)(dg + 1));   // +1 self loop
            run += dg;
        }
    }
    if (t == 1023) csr_off[n] = run;   // grand total (run of last thread)
}

// deg doubles as the per-node cursor (atomicSub); destroyed afterwards.
__global__ __launch_bounds__(TPB) void k_scatter(const int* __restrict__ srcv,
                                                 const int* __restrict__ dstv, int E,
                                                 const int* __restrict__ csr_off,
                                                 int* __restrict__ deg,
                                                 int* __restrict__ csr_src) {
    int i = blockIdx.x * TPB + threadIdx.x;
    if (i < E) {
        int d = dstv[i];
        int r = atomicSub(&deg[d], 1) - 1;
        csr_src[csr_off[d] + r] = srcv[i];
    }
}

// ---------------- GEMM1 (R21): barrier-free streaming bf16 MFMA ----------------
// C[r][j] = dinv[r] * sum_k A[r][k] * W[k][j], K=256, 64 cols.
// Block = 64 rows, 4 waves; wave = 16 rows x 64 cols (4 col-tiles 16x16).
// W staged ONCE to LDS as bf16 [c][k] (32KB) with XOR swizzle
// k ^ ((c&15)<<3). One barrier. K-loop: A fragments straight from global
// (wave-coalesced 16x128B), f32->bf16 in-register, 4 MFMAs; no barriers.
// C/D map (m89-verified): col=lane&15, row=(lane>>4)*4+reg.

__device__ __forceinline__ int swzW(int c, int k) {
    return c * 256 + (k ^ ((c & 15) << 3));
}

__global__ __launch_bounds__(TPB) void k_gemm1(const float* __restrict__ A,
                                               const float* __restrict__ W,
                                               const float* __restrict__ dinv,
                                               bfu* __restrict__ C, int n) {
    const int K = 256;
    __shared__ __align__(16) ushort Bh[64 * 256];   // 32 KB

    const int t = threadIdx.x;
    const int wave = t >> 6, lane = t & 63;
    const int rbase = blockIdx.x * 64;

    // ---- stage W once: thread t handles col c = t&63, k-range (t>>6)*64 ----
    {
        int c = t & 63;
        int kg = (t >> 6) << 6;   // 64 k's per wave
#pragma unroll
        for (int q = 0; q < 8; q++) {
            int k8 = kg + q * 8;
            ushort4 h0, h1;
#pragma unroll
            for (int j = 0; j < 4; j++) ((bfu*)&h0)[j] = f2bf(W[(size_t)(k8 + j) * 64 + c]);
#pragma unroll
            for (int j = 0; j < 4; j++) ((bfu*)&h1)[j] = f2bf(W[(size_t)(k8 + 4 + j) * 64 + c]);
            *(ushort4*)&Bh[swzW(c, k8)]     = h0;
            *(ushort4*)&Bh[swzW(c, k8) + 4] = h1;   // same 8-block, contiguous
        }
    }
    __syncthreads();   // the only barrier

    const int rl = lane & 15;            // row within tile / col within tile
    const int kg8 = (lane >> 4) << 3;    // k offset of this lane group
    int r0 = rbase + wave * 16 + rl;
    const float* arow = A + (size_t)(r0 < n ? r0 : (n - 1)) * K;

    f32x4 acc[4];
#pragma unroll
    for (int j = 0; j < 4; j++) acc[j] = {0.f, 0.f, 0.f, 0.f};

#pragma unroll
    for (int ks = 0; ks < 8; ks++) {
        int k0 = ks * 32 + kg8;
        float4 xa = *(const float4*)(arow + k0);
        float4 xb = *(const float4*)(arow + k0 + 4);
        s16x8 af;
        ((bfu*)&af)[0] = f2bf(xa.x);
        ((bfu*)&af)[1] = f2bf(xa.y);
        ((bfu*)&af)[2] = f2bf(xa.z);
        ((bfu*)&af)[3] = f2bf(xa.w);
        ((bfu*)&af)[4] = f2bf(xb.x);
        ((bfu*)&af)[5] = f2bf(xb.y);
        ((bfu*)&af)[6] = f2bf(xb.z);
        ((bfu*)&af)[7] = f2bf(xb.w);
#pragma unroll
        for (int ct = 0; ct < 4; ct++) {
            s16x8 bf = *(const s16x8*)&Bh[swzW(ct * 16 + rl, k0)];
            acc[ct] = __builtin_amdgcn_mfma_f32_16x16x32_bf16(af, bf, acc[ct], 0, 0, 0);
        }
    }

    // ---- epilogue: col = lane&15, row = (lane>>4)*4 + reg ----
    const int rq = (lane >> 4) << 2;
#pragma unroll
    for (int reg = 0; reg < 4; reg++) {
        int r = rbase + wave * 16 + rq + reg;
        if (r < n) {
            float d = dinv[r];
#pragma unroll
            for (int ct = 0; ct < 4; ct++) {
                C[(size_t)r * 64 + ct * 16 + rl] = f2bf(acc[ct][reg] * d);
            }
        }
    }
}

// ---------------- Aggregation (R19): wide row gather (dwordx4) ----------------
// Wave = 1 node. Lane map: g = lane>>3 (row slot 0..7), c = lane&7
// (8-feature chunk). One dwordx4 gather = 8 neighbor rows x 128B
// (16B/lane). Index load csr_src[p0+base+g]: broadcast in 8-lane groups,
// NO shfl. Feature totals via 3 shfl_xor rounds once per node.
// FUSE: per-wave 64x64 W2 matmul on the relu'd row (gemm2 fusion, R16).

__device__ __forceinline__ void acc_u4(float* acc, uint4 q) {
    acc[0] += blo(q.x); acc[1] += bhi(q.x);
    acc[2] += blo(q.y); acc[3] += bhi(q.y);
    acc[4] += blo(q.z); acc[5] += bhi(q.z);
    acc[6] += blo(q.w); acc[7] += bhi(q.w);
}

template <bool FUSE>
__global__ __launch_bounds__(TPB) void k_agg(const bfu* __restrict__ hs,
                                             const int* __restrict__ csr_off,
                                             const int* __restrict__ csr_src,
                                             const float* __restrict__ dinv,
                                             const float* __restrict__ bias,
                                             const float* __restrict__ W2,
                                             bfu* __restrict__ out, int n) {
    __shared__ float rowbuf[4][64];
    int wv = threadIdx.x >> 6;
    int node = blockIdx.x * 4 + wv;
    int lane = threadIdx.x & 63;
    int g = lane >> 3;             // row slot within batch
    int c = lane & 7;              // feature chunk (feats c*8 .. c*8+7)
    if (node >= n) return;
    int p0 = csr_off[node];
    int p1 = csr_off[node + 1];
    int deg = p1 - p0;
    float d = dinv[node];          // issue early, needed late

    // self row (hot line), added once after the cross-lane reduction
    uint4 selfv = *(const uint4*)(hs + (size_t)node * 64 + c * 8);

    float acc[8];
#pragma unroll
    for (int j = 0; j < 8; j++) acc[j] = 0.f;

    for (int base = 0; base < deg; base += 16) {
        int rem = deg - base;
        int li0 = p0 + base + g;
        if (rem > 8) {
            // slots 0..7 all valid; slots 8..15 predicated
            int li1 = li0 + 8;
            int idx0 = csr_src[li0];
            int idx1 = csr_src[li1 < p1 ? li1 : p0];
            bool v1 = (8 + g) < rem;
            uint4 q0 = *(const uint4*)(hs + (size_t)idx0 * 64 + c * 8);
            uint4 q1 = *(const uint4*)(hs + (size_t)(v1 ? idx1 : node) * 64 + c * 8);
            if (!v1) q1 = make_uint4(0u, 0u, 0u, 0u);
            acc_u4(acc, q0);
            acc_u4(acc, q1);
        } else {
            bool v0 = g < rem;
            int idx0 = csr_src[li0 < p1 ? li0 : p0];
            uint4 q0 = *(const uint4*)(hs + (size_t)(v0 ? idx0 : node) * 64 + c * 8);
            if (!v0) q0 = make_uint4(0u, 0u, 0u, 0u);
            acc_u4(acc, q0);
        }
    }

    // reduce across row-slot groups (lane bits 3,4,5)
#pragma unroll
    for (int j = 0; j < 8; j++) {
        acc[j] += __shfl_xor(acc[j], 8);
        acc[j] += __shfl_xor(acc[j], 16);
        acc[j] += __shfl_xor(acc[j], 32);
    }
    // self loop (each lane keeps a consistent replicated copy)
    acc_u4(acc, selfv);

    float4 b0 = *(const float4*)&bias[c * 8];
    float4 b1 = *(const float4*)&bias[c * 8 + 4];
    float v[8];
    v[0] = fmaxf(d * acc[0] + b0.x, 0.f);
    v[1] = fmaxf(d * acc[1] + b0.y, 0.f);
    v[2] = fmaxf(d * acc[2] + b0.z, 0.f);
    v[3] = fmaxf(d * acc[3] + b0.w, 0.f);
    v[4] = fmaxf(d * acc[4] + b1.x, 0.f);
    v[5] = fmaxf(d * acc[5] + b1.y, 0.f);
    v[6] = fmaxf(d * acc[6] + b1.z, 0.f);
    v[7] = fmaxf(d * acc[7] + b1.w, 0.f);

    if (!FUSE) {
        if (g == 0) {   // lanes 0..7 write the 128B row
            uint4 o;
            o.x = (unsigned)f2bf(v[0]) | ((unsigned)f2bf(v[1]) << 16);
            o.y = (unsigned)f2bf(v[2]) | ((unsigned)f2bf(v[3]) << 16);
            o.z = (unsigned)f2bf(v[4]) | ((unsigned)f2bf(v[5]) << 16);
            o.w = (unsigned)f2bf(v[6]) | ((unsigned)f2bf(v[7]) << 16);
            *(uint4*)(out + (size_t)node * 64 + c * 8) = o;
        }
    } else {
        // fused gemm2: out[node][lane] = f2bf(d * sum_k row[k] * W2[k][lane])
        if (g == 0) {
            *(float4*)&rowbuf[wv][c * 8]     = make_float4(v[0], v[1], v[2], v[3]);
            *(float4*)&rowbuf[wv][c * 8 + 4] = make_float4(v[4], v[5], v[6], v[7]);
        }
        __builtin_amdgcn_wave_barrier();   // ds_write before ds_read (same wave: HW in-order)
        float a = 0.f;
#pragma unroll 16
        for (int k = 0; k < 64; k++) a += rowbuf[wv][k] * W2[k * 64 + lane];
        out[(size_t)node * 64 + lane] = f2bf(d * a);
    }
}

// ---------------- Pool: sorted batch; uniform-chunk fast path (bf16 reads) ----------------

__global__ __launch_bounds__(TPB) void k_pool(const bfu* __restrict__ h,
                                              const int* __restrict__ batch, int n,
                                              float* __restrict__ gsum,
                                              int* __restrict__ gcnt) {
    const int CH = 16;
    int wid = blockIdx.x * 4 + (threadIdx.x >> 6);
    int lane = threadIdx.x & 63;
    int i0 = wid * CH;
    if (i0 >= n) return;
    int i1 = i0 + CH; if (i1 > n) i1 = n;
    int g0 = batch[i0];
    int g1 = batch[i1 - 1];
    if (g0 == g1) {
        float acc = 0.f;
#pragma unroll
        for (int i = 0; i < CH; i++) {
            int idx = i0 + i;
            if (idx < i1) acc += bf2f(h[(size_t)idx * 64 + lane]);
        }
        atomicAdd(&gsum[g0 * 64 + lane], acc);
        if (lane == 0) atomicAdd(&gcnt[g0], i1 - i0);
    } else {
        int cur = g0;
        float acc = 0.f;
        int cnt = 0;
        for (int i = i0; i < i1; i++) {
            int g = batch[i];
            if (g != cur) {
                atomicAdd(&gsum[cur * 64 + lane], acc);
                if (lane == 0) atomicAdd(&gcnt[cur], cnt);
                acc = 0.f; cnt = 0; cur = g;
            }
            acc += bf2f(h[(size_t)i * 64 + lane]);
            cnt++;
        }
        atomicAdd(&gsum[cur * 64 + lane], acc);
        if (lane == 0) atomicAdd(&gcnt[cur], cnt);
    }
}

// ---------------- Head, stage 1 ----------------

__global__ __launch_bounds__(TPB) void k_head1(const float* __restrict__ gsum,
                                               const int* __restrict__ gcnt,
                                               const float* __restrict__ fc1w,
                                               const float* __restrict__ fc1b,
                                               float* __restrict__ z) {
    int t = threadIdx.x;
    int g = blockIdx.x * 2 + (t >> 7);
    int o = t & 127;
    int c = gcnt[g]; if (c < 1) c = 1;
    float inv = 1.0f / (float)c;
    float a = fc1b[o];
#pragma unroll 16
    for (int j = 0; j < 64; j++) {
        float pj = gsum[g * 64 + j] * inv;
        a += pj * fc1w[j * 128 + o];
    }
    z[g * 128 + o] = fmaxf(a, 0.f);
}

// ---------------- Head, stage 2 ----------------

__global__ __launch_bounds__(TPB) void k_head2(const float* __restrict__ z,
                                               const float* __restrict__ fc2w,
                                               const float* __restrict__ fc2b,
                                               float* __restrict__ out) {
    int t = threadIdx.x;
    int g = t >> 2, c = t & 3;
    float a = fc2b[c];
#pragma unroll 16
    for (int o = 0; o < 128; o++) a += z[g * 128 + o] * fc2w[o * 4 + c];
    out[t] = a;
}

// ---------------- launch ----------------

extern "C" void kernel_launch(void* const* d_in, const int* in_sizes, int n_in,
                              void* d_out, int out_size, void* d_ws, size_t ws_size,
                              hipStream_t stream) {
    const float* x    = (const float*)d_in[0];
    const int*   ei   = (const int*)d_in[1];
    const int*   batch= (const int*)d_in[2];
    const float* W1   = (const float*)d_in[3];
    const float* b1   = (const float*)d_in[4];
    const float* W2   = (const float*)d_in[5];
    const float* b2   = (const float*)d_in[6];
    const float* fc1w = (const float*)d_in[7];
    const float* fc1b = (const float*)d_in[8];
    const float* fc2w = (const float*)d_in[9];
    const float* fc2b = (const float*)d_in[10];

    const int n = in_sizes[2];        // 50000
    const int E = in_sizes[1] / 2;    // 800000
    const int* srcv = ei;
    const int* dstv = ei + E;

    // workspace carve; zeroed region contiguous at front
    char* w = (char*)d_ws;
    float* gsum   = (float*)w;          w += 64 * 64 * 4;
    int*   gcnt   = (int*)w;            w += 64 * 4;
    int*   deg    = (int*)w;            w += (size_t)n * 4;
    size_t zbytes = (size_t)w - (size_t)d_ws;
    int*   csr_off= (int*)w;            w += (size_t)(n + 1) * 4;
    float* dinv   = (float*)w;          w += (size_t)n * 4;
    int*   csr_src= (int*)w;            w += (size_t)E * 4;
    float* zbuf   = (float*)w;          w += 64 * 128 * 4;
    w = (char*)(((size_t)w + 255) & ~(size_t)255);
    bfu* hs = (bfu*)w;                  w += (size_t)n * 64 * 2;
    w = (char*)(((size_t)w + 255) & ~(size_t)255);
    bfu* hb = (bfu*)w;                  w += (size_t)n * 64 * 2;

    hipMemsetAsync(d_ws, 0, zbytes, stream);

    int gE = (E + TPB - 1) / TPB;   // 3125
    k_deg<<<gE, TPB, 0, stream>>>(dstv, E, deg);
    k_scan<<<1, 1024, 0, stream>>>(deg, n, csr_off, dinv);
    k_scatter<<<gE, TPB, 0, stream>>>(srcv, dstv, E, csr_off, deg, csr_src);

    int gRows = (n + 63) / 64;   // 782
    int gNode = (n + 3) / 4;
    // layer 1 gemm: x*W1*dinv -> hs (barrier-free streaming bf16 MFMA)
    k_gemm1<<<gRows, TPB, 0, stream>>>(x, W1, dinv, hs, n);
    // agg1 + fused gemm2: hs -> (agg,relu,+b1) -> *W2*dinv -> hb
    k_agg<true><<<gNode, TPB, 0, stream>>>(hs, csr_off, csr_src, dinv, b1, W2, hb, n);
    // agg2: hb -> (agg,relu,+b2) -> hs
    k_agg<false><<<gNode, TPB, 0, stream>>>(hb, csr_off, csr_src, dinv, b2, nullptr, hs, n);

    int nwaves16 = (n + 15) / 16;
    k_pool<<<(nwaves16 + 3) / 4, TPB, 0, stream>>>(hs, batch, n, gsum, gcnt);
    k_head1<<<32, TPB, 0, stream>>>(gsum, gcnt, fc1w, fc1b, zbuf);
    k_head2<<<1, TPB, 0, stream>>>(zbuf, fc2w, fc2b, (float*)d_out);
}

// Round 11
// 224.048 us; speedup vs baseline: 1.7928x; 1.7928x over previous
//
#include <hip/hip_runtime.h>

// GNN: 2x GCNConv(relu) + mean-pool + MLP head.
// Sizes fixed: N=50000, E=800000, F_IN=256, H=64, NC=4, NG=64.
//
// R9: hs/hb bf16, f32 accumulate. R11/R19: wide packed gather.
// R15: decomposition: pool+head1+head2 = 2.6us, dispatch overhead ~0.
// R16: gemm2 fused into agg1 (free) -> kept.
// R17-R19: agg converges at 42.5us, FETCH 33MB invariant (TCC wall).
// R20/R21: gemm1 pure-bf16 + barrier-free streaming (235.6 total).
// R22: atomic CSR build REGRESSED (401.7): single-block scan = 123.6us
//      (1-CU latency serialization); 800k device atomics ~60us/kernel
//      (cross-XCD same-line thrash). Also settled: harness fill (42.5)
//      IS inside dur_us -> gemm1+passA+passB ~= 105us combined.
// R23 (this round): revert to LDS-bucket-sort CSR build, de-serialized:
//      - 8-round/16-barrier LDS scans -> wave __shfl_up scan + 1 barrier;
//      - passA: edges kept in registers; thread-per-edge copyout via
//        bktl[] byte array (kills 49-iter serial bucket loop);
//      - passB: staged copy-in over full BCAP (no cnt dependency, loads
//        issue at kernel start); base/cnt from the scanned sboff.
//      196 blocks co-resident -> kernel time ~= single-block latency.

#define TPB 256
#define CHUNK_A 4096
#define BCAP 4608          // per-bucket staging capacity (mean 4096, +8 sigma)

typedef unsigned short bfu;
typedef __attribute__((ext_vector_type(8))) short s16x8;
typedef __attribute__((ext_vector_type(4))) float f32x4;

__device__ __forceinline__ float bf2f(bfu u) {
    union { unsigned u32; float f; } c; c.u32 = ((unsigned)u) << 16; return c.f;
}
__device__ __forceinline__ bfu f2bf(float f) {
    union { float f; unsigned u; } c; c.f = f;
    unsigned r = 0x7FFFu + ((c.u >> 16) & 1u);     // round-to-nearest-even
    return (bfu)((c.u + r) >> 16);
}
__device__ __forceinline__ float blo(unsigned w) {
    union { unsigned u32; float f; } c; c.u32 = w << 16; return c.f;
}
__device__ __forceinline__ float bhi(unsigned w) {
    union { unsigned u32; float f; } c; c.u32 = w & 0xFFFF0000u; return c.f;
}

// wave-level inclusive scan (Hillis-Steele over 64 lanes, register-only)
__device__ __forceinline__ int wave_iscan(int s, int lane) {
#pragma unroll
    for (int off = 1; off < 64; off <<= 1) {
        int u = __shfl_up(s, off);
        if (lane >= off) s += u;
    }
    return s;
}

// ---------------- pass A: chunked bucket staging (R23 de-serialized) ----------------
// packed edge: (src<<8) | (dst & 255); requires n <= 65536, nbuck <= 256.

__global__ __launch_bounds__(TPB) void k_passA(const int* __restrict__ srcv,
                                               const int* __restrict__ dstv, int E,
                                               int* __restrict__ gcur,
                                               int* __restrict__ staged, int nbuck) {
    __shared__ int pk[CHUNK_A];
    __shared__ unsigned char bktl[CHUNK_A];
    __shared__ int hist[256];
    __shared__ int ebase[256];
    __shared__ int gbase[256];
    __shared__ int lcur[256];
    __shared__ int wsum[4];
    int t = threadIdx.x;
    int lane = t & 63, wv = t >> 6;
    int e0 = blockIdx.x * CHUNK_A;
    int e1 = e0 + CHUNK_A; if (e1 > E) e1 = E;
    int cblk = e1 - e0;

    hist[t] = 0; lcur[t] = 0;
    __syncthreads();

    // edges into registers (one global read each)
    int myd[16], mys[16];
#pragma unroll
    for (int q = 0; q < 16; q++) {
        int i = e0 + t + q * TPB;
        myd[q] = (i < e1) ? dstv[i] : -1;
    }
#pragma unroll
    for (int q = 0; q < 16; q++) {
        int i = e0 + t + q * TPB;
        mys[q] = (i < e1) ? srcv[i] : 0;
    }
#pragma unroll
    for (int q = 0; q < 16; q++)
        if (myd[q] >= 0) atomicAdd(&hist[myd[q] >> 8], 1);
    __syncthreads();

    // exclusive prefix of hist via wave shfl scan (1 barrier)
    int v = hist[t];
    int s = wave_iscan(v, lane);
    if (lane == 63) wsum[wv] = s;
    __syncthreads();
    int add = 0;
    if (wv > 0) add += wsum[0];
    if (wv > 1) add += wsum[1];
    if (wv > 2) add += wsum[2];
    int eb = add + s - v;
    ebase[t] = eb;
    if (t < nbuck && v > 0) gbase[t] = t * BCAP + atomicAdd(&gcur[t], v);
    __syncthreads();

    // scatter into pk (bucket-sorted), record bucket per slot
#pragma unroll
    for (int q = 0; q < 16; q++) {
        int d = myd[q];
        if (d >= 0) {
            int b = d >> 8;
            int r = atomicAdd(&lcur[b], 1);
            int p = ebase[b] + r;
            pk[p] = (mys[q] << 8) | (d & 255);
            bktl[p] = (unsigned char)b;
        }
    }
    __syncthreads();

    // thread-per-edge copyout
    for (int i = t; i < cblk; i += TPB) {
        int b = bktl[i];
        staged[gbase[b] + (i - ebase[b])] = pk[i];
    }
}

// ---------------- pass B: per-bucket node sort + csr_off + dinv (R23) ----------------

__global__ __launch_bounds__(TPB) void k_passB(const int* __restrict__ staged,
                                               const int* __restrict__ gcur,
                                               int* __restrict__ csr_off,
                                               int* __restrict__ csr_src,
                                               float* __restrict__ dinv,
                                               int n, int nbuck) {
    __shared__ int pk[BCAP];
    __shared__ int hist[256];
    __shared__ int nbase[256];
    __shared__ int cur[256];
    __shared__ int sboff[256];
    __shared__ int wsum[4];
    int b = blockIdx.x;
    int t = threadIdx.x;
    int lane = t & 63, wv = t >> 6;
    int n0 = b << 8;
    int n1 = n0 + 256; if (n1 > n) n1 = n;

    hist[t] = 0; cur[t] = 0;
    int cv = (t < nbuck) ? gcur[t] : 0;
    // copy-in over full BCAP: no dependency on cnt, loads issue immediately
    for (int i = t; i < BCAP; i += TPB) pk[i] = staged[b * BCAP + i];
    // scan of gcur (bucket totals) while loads are in flight
    int s1 = wave_iscan(cv, lane);
    if (lane == 63) wsum[wv] = s1;
    __syncthreads();   // #1: init, pk, wsum visible
    int add1 = 0;
    if (wv > 0) add1 += wsum[0];
    if (wv > 1) add1 += wsum[1];
    if (wv > 2) add1 += wsum[2];
    sboff[t] = add1 + s1;   // inclusive prefix
    __syncthreads();   // #2: sboff visible
    int base = (b == 0) ? 0 : sboff[b - 1];
    int cnt = sboff[b] - base;

    for (int i = t; i < cnt; i += TPB) atomicAdd(&hist[pk[i] & 255], 1);
    __syncthreads();   // #3: hist complete

    int v = hist[t];
    int s2 = wave_iscan(v, lane);
    if (lane == 63) wsum[wv] = s2;
    __syncthreads();   // #4: wsum (2nd) visible
    int add2 = 0;
    if (wv > 0) add2 += wsum[0];
    if (wv > 1) add2 += wsum[1];
    if (wv > 2) add2 += wsum[2];
    int nb = add2 + s2 - v;
    nbase[t] = nb;
    if (n0 + t < n1) {
        csr_off[n0 + t] = base + nb;
        dinv[n0 + t] = rsqrtf((float)(v + 1));   // +1 self loop
    }
    if (b == nbuck - 1 && t == 0) csr_off[n] = base + cnt;
    __syncthreads();   // #5: nbase visible

    for (int i = t; i < cnt; i += TPB) {
        int p = pk[i];
        int dloc = p & 255;
        int r = atomicAdd(&cur[dloc], 1);
        csr_src[base + nbase[dloc] + r] = p >> 8;
    }
}

// ---------------- GEMM1 (R21): barrier-free streaming bf16 MFMA ----------------
// C[r][j] = dinv[r] * sum_k A[r][k] * W[k][j], K=256, 64 cols.
// Block = 64 rows, 4 waves; wave = 16 rows x 64 cols (4 col-tiles 16x16).
// W staged ONCE to LDS as bf16 [c][k] (32KB) with XOR swizzle
// k ^ ((c&15)<<3). One barrier. K-loop: A fragments straight from global
// (wave-coalesced 16x128B), f32->bf16 in-register, 4 MFMAs; no barriers.
// C/D map (m89-verified): col=lane&15, row=(lane>>4)*4+reg.

__device__ __forceinline__ int swzW(int c, int k) {
    return c * 256 + (k ^ ((c & 15) << 3));
}

__global__ __launch_bounds__(TPB) void k_gemm1(const float* __restrict__ A,
                                               const float* __restrict__ W,
                                               const float* __restrict__ dinv,
                                               bfu* __restrict__ C, int n) {
    const int K = 256;
    __shared__ __align__(16) ushort Bh[64 * 256];   // 32 KB

    const int t = threadIdx.x;
    const int wave = t >> 6, lane = t & 63;
    const int rbase = blockIdx.x * 64;

    // ---- stage W once: thread t handles col c = t&63, k-range (t>>6)*64 ----
    {
        int c = t & 63;
        int kg = (t >> 6) << 6;   // 64 k's per wave
#pragma unroll
        for (int q = 0; q < 8; q++) {
            int k8 = kg + q * 8;
            ushort4 h0, h1;
#pragma unroll
            for (int j = 0; j < 4; j++) ((bfu*)&h0)[j] = f2bf(W[(size_t)(k8 + j) * 64 + c]);
#pragma unroll
            for (int j = 0; j < 4; j++) ((bfu*)&h1)[j] = f2bf(W[(size_t)(k8 + 4 + j) * 64 + c]);
            *(ushort4*)&Bh[swzW(c, k8)]     = h0;
            *(ushort4*)&Bh[swzW(c, k8) + 4] = h1;   // same 8-block, contiguous
        }
    }
    __syncthreads();   // the only barrier

    const int rl = lane & 15;            // row within tile / col within tile
    const int kg8 = (lane >> 4) << 3;    // k offset of this lane group
    int r0 = rbase + wave * 16 + rl;
    const float* arow = A + (size_t)(r0 < n ? r0 : (n - 1)) * K;

    f32x4 acc[4];
#pragma unroll
    for (int j = 0; j < 4; j++) acc[j] = {0.f, 0.f, 0.f, 0.f};

#pragma unroll
    for (int ks = 0; ks < 8; ks++) {
        int k0 = ks * 32 + kg8;
        float4 xa = *(const float4*)(arow + k0);
        float4 xb = *(const float4*)(arow + k0 + 4);
        s16x8 af;
        ((bfu*)&af)[0] = f2bf(xa.x);
        ((bfu*)&af)[1] = f2bf(xa.y);
        ((bfu*)&af)[2] = f2bf(xa.z);
        ((bfu*)&af)[3] = f2bf(xa.w);
        ((bfu*)&af)[4] = f2bf(xb.x);
        ((bfu*)&af)[5] = f2bf(xb.y);
        ((bfu*)&af)[6] = f2bf(xb.z);
        ((bfu*)&af)[7] = f2bf(xb.w);
#pragma unroll
        for (int ct = 0; ct < 4; ct++) {
            s16x8 bf = *(const s16x8*)&Bh[swzW(ct * 16 + rl, k0)];
            acc[ct] = __builtin_amdgcn_mfma_f32_16x16x32_bf16(af, bf, acc[ct], 0, 0, 0);
        }
    }

    // ---- epilogue: col = lane&15, row = (lane>>4)*4 + reg ----
    const int rq = (lane >> 4) << 2;
#pragma unroll
    for (int reg = 0; reg < 4; reg++) {
        int r = rbase + wave * 16 + rq + reg;
        if (r < n) {
            float d = dinv[r];
#pragma unroll
            for (int ct = 0; ct < 4; ct++) {
                C[(size_t)r * 64 + ct * 16 + rl] = f2bf(acc[ct][reg] * d);
            }
        }
    }
}

// ---------------- Aggregation (R19): wide row gather (dwordx4) ----------------
// Wave = 1 node. Lane map: g = lane>>3 (row slot 0..7), c = lane&7
// (8-feature chunk). One dwordx4 gather = 8 neighbor rows x 128B
// (16B/lane). Index load csr_src[p0+base+g]: broadcast in 8-lane groups,
// NO shfl. Feature totals via 3 shfl_xor rounds once per node.
// FUSE: per-wave 64x64 W2 matmul on the relu'd row (gemm2 fusion, R16).

__device__ __forceinline__ void acc_u4(float* acc, uint4 q) {
    acc[0] += blo(q.x); acc[1] += bhi(q.x);
    acc[2] += blo(q.y); acc[3] += bhi(q.y);
    acc[4] += blo(q.z); acc[5] += bhi(q.z);
    acc[6] += blo(q.w); acc[7] += bhi(q.w);
}

template <bool FUSE>
__global__ __launch_bounds__(TPB) void k_agg(const bfu* __restrict__ hs,
                                             const int* __restrict__ csr_off,
                                             const int* __restrict__ csr_src,
                                             const float* __restrict__ dinv,
                                             const float* __restrict__ bias,
                                             const float* __restrict__ W2,
                                             bfu* __restrict__ out, int n) {
    __shared__ float rowbuf[4][64];
    int wv = threadIdx.x >> 6;
    int node = blockIdx.x * 4 + wv;
    int lane = threadIdx.x & 63;
    int g = lane >> 3;             // row slot within batch
    int c = lane & 7;              // feature chunk (feats c*8 .. c*8+7)
    if (node >= n) return;
    int p0 = csr_off[node];
    int p1 = csr_off[node + 1];
    int deg = p1 - p0;
    float d = dinv[node];          // issue early, needed late

    // self row (hot line), added once after the cross-lane reduction
    uint4 selfv = *(const uint4*)(hs + (size_t)node * 64 + c * 8);

    float acc[8];
#pragma unroll
    for (int j = 0; j < 8; j++) acc[j] = 0.f;

    for (int base = 0; base < deg; base += 16) {
        int rem = deg - base;
        int li0 = p0 + base + g;
        if (rem > 8) {
            // slots 0..7 all valid; slots 8..15 predicated
            int li1 = li0 + 8;
            int idx0 = csr_src[li0];
            int idx1 = csr_src[li1 < p1 ? li1 : p0];
            bool v1 = (8 + g) < rem;
            uint4 q0 = *(const uint4*)(hs + (size_t)idx0 * 64 + c * 8);
            uint4 q1 = *(const uint4*)(hs + (size_t)(v1 ? idx1 : node) * 64 + c * 8);
            if (!v1) q1 = make_uint4(0u, 0u, 0u, 0u);
            acc_u4(acc, q0);
            acc_u4(acc, q1);
        } else {
            bool v0 = g < rem;
            int idx0 = csr_src[li0 < p1 ? li0 : p0];
            uint4 q0 = *(const uint4*)(hs + (size_t)(v0 ? idx0 : node) * 64 + c * 8);
            if (!v0) q0 = make_uint4(0u, 0u, 0u, 0u);
            acc_u4(acc, q0);
        }
    }

    // reduce across row-slot groups (lane bits 3,4,5)
#pragma unroll
    for (int j = 0; j < 8; j++) {
        acc[j] += __shfl_xor(acc[j], 8);
        acc[j] += __shfl_xor(acc[j], 16);
        acc[j] += __shfl_xor(acc[j], 32);
    }
    // self loop (each lane keeps a consistent replicated copy)
    acc_u4(acc, selfv);

    float4 b0 = *(const float4*)&bias[c * 8];
    float4 b1 = *(const float4*)&bias[c * 8 + 4];
    float v[8];
    v[0] = fmaxf(d * acc[0] + b0.x, 0.f);
    v[1] = fmaxf(d * acc[1] + b0.y, 0.f);
    v[2] = fmaxf(d * acc[2] + b0.z, 0.f);
    v[3] = fmaxf(d * acc[3] + b0.w, 0.f);
    v[4] = fmaxf(d * acc[4] + b1.x, 0.f);
    v[5] = fmaxf(d * acc[5] + b1.y, 0.f);
    v[6] = fmaxf(d * acc[6] + b1.z, 0.f);
    v[7] = fmaxf(d * acc[7] + b1.w, 0.f);

    if (!FUSE) {
        if (g == 0) {   // lanes 0..7 write the 128B row
            uint4 o;
            o.x = (unsigned)f2bf(v[0]) | ((unsigned)f2bf(v[1]) << 16);
            o.y = (unsigned)f2bf(v[2]) | ((unsigned)f2bf(v[3]) << 16);
            o.z = (unsigned)f2bf(v[4]) | ((unsigned)f2bf(v[5]) << 16);
            o.w = (unsigned)f2bf(v[6]) | ((unsigned)f2bf(v[7]) << 16);
            *(uint4*)(out + (size_t)node * 64 + c * 8) = o;
        }
    } else {
        // fused gemm2: out[node][lane] = f2bf(d * sum_k row[k] * W2[k][lane])
        if (g == 0) {
            *(float4*)&rowbuf[wv][c * 8]     = make_float4(v[0], v[1], v[2], v[3]);
            *(float4*)&rowbuf[wv][c * 8 + 4] = make_float4(v[4], v[5], v[6], v[7]);
        }
        __builtin_amdgcn_wave_barrier();   // ds_write before ds_read (same wave: HW in-order)
        float a = 0.f;
#pragma unroll 16
        for (int k = 0; k < 64; k++) a += rowbuf[wv][k] * W2[k * 64 + lane];
        out[(size_t)node * 64 + lane] = f2bf(d * a);
    }
}

// ---------------- Pool: sorted batch; uniform-chunk fast path (bf16 reads) ----------------

__global__ __launch_bounds__(TPB) void k_pool(const bfu* __restrict__ h,
                                              const int* __restrict__ batch, int n,
                                              float* __restrict__ gsum,
                                              int* __restrict__ gcnt) {
    const int CH = 16;
    int wid = blockIdx.x * 4 + (threadIdx.x >> 6);
    int lane = threadIdx.x & 63;
    int i0 = wid * CH;
    if (i0 >= n) return;
    int i1 = i0 + CH; if (i1 > n) i1 = n;
    int g0 = batch[i0];
    int g1 = batch[i1 - 1];
    if (g0 == g1) {
        float acc = 0.f;
#pragma unroll
        for (int i = 0; i < CH; i++) {
            int idx = i0 + i;
            if (idx < i1) acc += bf2f(h[(size_t)idx * 64 + lane]);
        }
        atomicAdd(&gsum[g0 * 64 + lane], acc);
        if (lane == 0) atomicAdd(&gcnt[g0], i1 - i0);
    } else {
        int cur = g0;
        float acc = 0.f;
        int cnt = 0;
        for (int i = i0; i < i1; i++) {
            int g = batch[i];
            if (g != cur) {
                atomicAdd(&gsum[cur * 64 + lane], acc);
                if (lane == 0) atomicAdd(&gcnt[cur], cnt);
                acc = 0.f; cnt = 0; cur = g;
            }
            acc += bf2f(h[(size_t)i * 64 + lane]);
            cnt++;
        }
        atomicAdd(&gsum[cur * 64 + lane], acc);
        if (lane == 0) atomicAdd(&gcnt[cur], cnt);
    }
}

// ---------------- Head, stage 1 ----------------

__global__ __launch_bounds__(TPB) void k_head1(const float* __restrict__ gsum,
                                               const int* __restrict__ gcnt,
                                               const float* __restrict__ fc1w,
                                               const float* __restrict__ fc1b,
                                               float* __restrict__ z) {
    int t = threadIdx.x;
    int g = blockIdx.x * 2 + (t >> 7);
    int o = t & 127;
    int c = gcnt[g]; if (c < 1) c = 1;
    float inv = 1.0f / (float)c;
    float a = fc1b[o];
#pragma unroll 16
    for (int j = 0; j < 64; j++) {
        float pj = gsum[g * 64 + j] * inv;
        a += pj * fc1w[j * 128 + o];
    }
    z[g * 128 + o] = fmaxf(a, 0.f);
}

// ---------------- Head, stage 2 ----------------

__global__ __launch_bounds__(TPB) void k_head2(const float* __restrict__ z,
                                               const float* __restrict__ fc2w,
                                               const float* __restrict__ fc2b,
                                               float* __restrict__ out) {
    int t = threadIdx.x;
    int g = t >> 2, c = t & 3;
    float a = fc2b[c];
#pragma unroll 16
    for (int o = 0; o < 128; o++) a += z[g * 128 + o] * fc2w[o * 4 + c];
    out[t] = a;
}

// ---------------- launch ----------------

extern "C" void kernel_launch(void* const* d_in, const int* in_sizes, int n_in,
                              void* d_out, int out_size, void* d_ws, size_t ws_size,
                              hipStream_t stream) {
    const float* x    = (const float*)d_in[0];
    const int*   ei   = (const int*)d_in[1];
    const int*   batch= (const int*)d_in[2];
    const float* W1   = (const float*)d_in[3];
    const float* b1   = (const float*)d_in[4];
    const float* W2   = (const float*)d_in[5];
    const float* b2   = (const float*)d_in[6];
    const float* fc1w = (const float*)d_in[7];
    const float* fc1b = (const float*)d_in[8];
    const float* fc2w = (const float*)d_in[9];
    const float* fc2b = (const float*)d_in[10];

    const int n = in_sizes[2];        // 50000
    const int E = in_sizes[1] / 2;    // 800000
    const int* srcv = ei;
    const int* dstv = ei + E;
    const int nbuck = (n + 255) >> 8; // 196 (must be <= 256)

    // workspace carve; zeroed region contiguous at front
    char* w = (char*)d_ws;
    int*   gcur   = (int*)w;            w += 256 * 4;
    int*   gcnt   = (int*)w;            w += 64 * 4;
    float* gsum   = (float*)w;          w += 64 * 64 * 4;
    size_t zbytes = (size_t)w - (size_t)d_ws;
    int*   csr_off= (int*)w;            w += (size_t)(n + 1) * 4;
    float* dinv   = (float*)w;          w += (size_t)n * 4;
    int*   csr_src= (int*)w;            w += (size_t)E * 4;
    int*   staged = (int*)w;            w += (size_t)nbuck * BCAP * 4;
    float* zbuf   = (float*)w;          w += 64 * 128 * 4;
    w = (char*)(((size_t)w + 255) & ~(size_t)255);
    bfu* hs = (bfu*)w;                  w += (size_t)n * 64 * 2;
    w = (char*)(((size_t)w + 255) & ~(size_t)255);
    bfu* hb = (bfu*)w;                  w += (size_t)n * 64 * 2;

    hipMemsetAsync(d_ws, 0, zbytes, stream);

    int gA = (E + CHUNK_A - 1) / CHUNK_A;   // 196
    k_passA<<<gA, TPB, 0, stream>>>(srcv, dstv, E, gcur, staged, nbuck);
    k_passB<<<nbuck, TPB, 0, stream>>>(staged, gcur, csr_off, csr_src, dinv, n, nbuck);

    int gRows = (n + 63) / 64;   // 782
    int gNode = (n + 3) / 4;
    // layer 1 gemm: x*W1*dinv -> hs (barrier-free streaming bf16 MFMA)
    k_gemm1<<<gRows, TPB, 0, stream>>>(x, W1, dinv, hs, n);
    // agg1 + fused gemm2: hs -> (agg,relu,+b1) -> *W2*dinv -> hb
    k_agg<true><<<gNode, TPB, 0, stream>>>(hs, csr_off, csr_src, dinv, b1, W2, hb, n);
    // agg2: hb -> (agg,relu,+b2) -> hs
    k_agg<false><<<gNode, TPB, 0, stream>>>(hb, csr_off, csr_src, dinv, b2, nullptr, hs, n);

    int nwaves16 = (n + 15) / 16;
    k_pool<<<(nwaves16 + 3) / 4, TPB, 0, stream>>>(hs, batch, n, gsum, gcnt);
    k_head1<<<32, TPB, 0, stream>>>(gsum, gcnt, fc1w, fc1b, zbuf);
    k_head2<<<1, TPB, 0, stream>>>(zbuf, fc2w, fc2b, (float*)d_out);
}

// Round 12
// 217.927 us; speedup vs baseline: 1.8432x; 1.0281x over previous
//
#include <hip/hip_runtime.h>

// GNN: 2x GCNConv(relu) + mean-pool + MLP head.
// Sizes fixed: N=50000, E=800000, F_IN=256, H=64, NC=4, NG=64.
//
// R9: hs/hb bf16, f32 accumulate. R11/R19: wide packed gather.
// R15: decomposition: pool+head1+head2 = 2.6us, dispatch overhead ~0;
//      harness fill (~42.5us) counts inside dur_us (settled R22).
// R16: gemm2 fused into agg1 (free) -> kept.
// R17-R19: agg converges at 42.5us, FETCH 33MB invariant (TCC wall).
// R20/R21: gemm1 pure-bf16 + barrier-free streaming.
// R22: atomic CSR build regressed (1-CU scan 123us; 800k device atomics).
// R23: shfl-scan de-serialized passA/passB: 235.6 -> 224.0.
// R24 (this round): CONCURRENCY. passA and gemm1 are independent
//      (gemm1 needed dinv only for the output scale) -> merged into ONE
//      dispatch k_fused1 (196 passA blocks + 782 gemm1 blocks, 32KB LDS
//      union): latency stalls of each hide under the other's work.
//      gemm1 writes UNSCALED bf16 xW1; passB (which computes dinv) also
//      scales its 256 hs rows (+~1-2us, no extra dispatch). 10 -> 8
//      dispatches; serial gemm1+passA -> max(gemm1, passA).

#define TPB 256
#define CHUNK_A 4096
#define BCAP 4608          // per-bucket staging capacity (mean 4096, +8 sigma)

typedef unsigned short bfu;
typedef __attribute__((ext_vector_type(8))) short s16x8;
typedef __attribute__((ext_vector_type(4))) float f32x4;

__device__ __forceinline__ float bf2f(bfu u) {
    union { unsigned u32; float f; } c; c.u32 = ((unsigned)u) << 16; return c.f;
}
__device__ __forceinline__ bfu f2bf(float f) {
    union { float f; unsigned u; } c; c.f = f;
    unsigned r = 0x7FFFu + ((c.u >> 16) & 1u);     // round-to-nearest-even
    return (bfu)((c.u + r) >> 16);
}
__device__ __forceinline__ float blo(unsigned w) {
    union { unsigned u32; float f; } c; c.u32 = w << 16; return c.f;
}
__device__ __forceinline__ float bhi(unsigned w) {
    union { unsigned u32; float f; } c; c.u32 = w & 0xFFFF0000u; return c.f;
}

// wave-level inclusive scan (Hillis-Steele over 64 lanes, register-only)
__device__ __forceinline__ int wave_iscan(int s, int lane) {
#pragma unroll
    for (int off = 1; off < 64; off <<= 1) {
        int u = __shfl_up(s, off);
        if (lane >= off) s += u;
    }
    return s;
}

__device__ __forceinline__ int swzW(int c, int k) {
    return c * 256 + (k ^ ((c & 15) << 3));
}

// ---------------- fused dispatch 1: passA (blocks < gA) || gemm1 (rest) ----------------
// passA: chunked bucket staging (R23 de-serialized). packed edge:
//   (src<<8)|(dst&255); requires n <= 65536, nbuck <= 256.
// gemm1: barrier-free streaming bf16 MFMA, UNSCALED output (dinv applied
//   later in passB). W staged once to 32KB LDS ([c][k], XOR swizzle);
//   A fragments straight from global; C/D map col=lane&15,
//   row=(lane>>4)*4+reg (m89-verified).
// LDS union: passA uses 24.6KB inside gemm1's 32KB Bh region.

__global__ __launch_bounds__(TPB) void k_fused1(const int* __restrict__ srcv,
                                                const int* __restrict__ dstv, int E,
                                                int* __restrict__ gcur,
                                                int* __restrict__ staged, int nbuck,
                                                int gA,
                                                const float* __restrict__ A,
                                                const float* __restrict__ W,
                                                bfu* __restrict__ C, int n) {
    __shared__ __align__(16) char smem[32768];
    int t = threadIdx.x;
    int lane = t & 63, wv = t >> 6;

    if ((int)blockIdx.x < gA) {
        // ================= passA =================
        int* pk = (int*)smem;                                  // 16384 B
        unsigned char* bktl = (unsigned char*)(smem + 16384);  //  4096 B
        int* hist  = (int*)(smem + 20480);                     //  1024 B
        int* ebase = (int*)(smem + 21504);
        int* gbase = (int*)(smem + 22528);
        int* lcur  = (int*)(smem + 23552);
        int* wsum  = (int*)(smem + 24576);                     //    16 B
        int e0 = blockIdx.x * CHUNK_A;
        int e1 = e0 + CHUNK_A; if (e1 > E) e1 = E;
        int cblk = e1 - e0;

        hist[t] = 0; lcur[t] = 0;
        __syncthreads();

        int myd[16], mys[16];
#pragma unroll
        for (int q = 0; q < 16; q++) {
            int i = e0 + t + q * TPB;
            myd[q] = (i < e1) ? dstv[i] : -1;
        }
#pragma unroll
        for (int q = 0; q < 16; q++) {
            int i = e0 + t + q * TPB;
            mys[q] = (i < e1) ? srcv[i] : 0;
        }
#pragma unroll
        for (int q = 0; q < 16; q++)
            if (myd[q] >= 0) atomicAdd(&hist[myd[q] >> 8], 1);
        __syncthreads();

        int v = hist[t];
        int s = wave_iscan(v, lane);
        if (lane == 63) wsum[wv] = s;
        __syncthreads();
        int add = 0;
        if (wv > 0) add += wsum[0];
        if (wv > 1) add += wsum[1];
        if (wv > 2) add += wsum[2];
        int eb = add + s - v;
        ebase[t] = eb;
        if (t < nbuck && v > 0) gbase[t] = t * BCAP + atomicAdd(&gcur[t], v);
        __syncthreads();

#pragma unroll
        for (int q = 0; q < 16; q++) {
            int d = myd[q];
            if (d >= 0) {
                int b = d >> 8;
                int r = atomicAdd(&lcur[b], 1);
                int p = ebase[b] + r;
                pk[p] = (mys[q] << 8) | (d & 255);
                bktl[p] = (unsigned char)b;
            }
        }
        __syncthreads();

        for (int i = t; i < cblk; i += TPB) {
            int b = bktl[i];
            staged[gbase[b] + (i - ebase[b])] = pk[i];
        }
    } else {
        // ================= gemm1 (unscaled) =================
        const int K = 256;
        ushort* Bh = (ushort*)smem;    // 32 KB
        const int rbase = ((int)blockIdx.x - gA) * 64;

        {   // stage W once: col c = t&63, k-range (t>>6)*64
            int c = t & 63;
            int kg = (t >> 6) << 6;
#pragma unroll
            for (int q = 0; q < 8; q++) {
                int k8 = kg + q * 8;
                ushort4 h0, h1;
#pragma unroll
                for (int j = 0; j < 4; j++) ((bfu*)&h0)[j] = f2bf(W[(size_t)(k8 + j) * 64 + c]);
#pragma unroll
                for (int j = 0; j < 4; j++) ((bfu*)&h1)[j] = f2bf(W[(size_t)(k8 + 4 + j) * 64 + c]);
                *(ushort4*)&Bh[swzW(c, k8)]     = h0;
                *(ushort4*)&Bh[swzW(c, k8) + 4] = h1;
            }
        }
        __syncthreads();   // only barrier in this branch

        const int rl = lane & 15;
        const int kg8 = (lane >> 4) << 3;
        int r0 = rbase + wv * 16 + rl;
        const float* arow = A + (size_t)(r0 < n ? r0 : (n - 1)) * K;

        f32x4 acc[4];
#pragma unroll
        for (int j = 0; j < 4; j++) acc[j] = {0.f, 0.f, 0.f, 0.f};

#pragma unroll
        for (int ks = 0; ks < 8; ks++) {
            int k0 = ks * 32 + kg8;
            float4 xa = *(const float4*)(arow + k0);
            float4 xb = *(const float4*)(arow + k0 + 4);
            s16x8 af;
            ((bfu*)&af)[0] = f2bf(xa.x);
            ((bfu*)&af)[1] = f2bf(xa.y);
            ((bfu*)&af)[2] = f2bf(xa.z);
            ((bfu*)&af)[3] = f2bf(xa.w);
            ((bfu*)&af)[4] = f2bf(xb.x);
            ((bfu*)&af)[5] = f2bf(xb.y);
            ((bfu*)&af)[6] = f2bf(xb.z);
            ((bfu*)&af)[7] = f2bf(xb.w);
#pragma unroll
            for (int ct = 0; ct < 4; ct++) {
                s16x8 bf = *(const s16x8*)&Bh[swzW(ct * 16 + rl, k0)];
                acc[ct] = __builtin_amdgcn_mfma_f32_16x16x32_bf16(af, bf, acc[ct], 0, 0, 0);
            }
        }

        const int rq = (lane >> 4) << 2;
#pragma unroll
        for (int reg = 0; reg < 4; reg++) {
            int r = rbase + wv * 16 + rq + reg;
            if (r < n) {
#pragma unroll
                for (int ct = 0; ct < 4; ct++) {
                    C[(size_t)r * 64 + ct * 16 + rl] = f2bf(acc[ct][reg]);
                }
            }
        }
    }
}

// ---------------- pass B: node sort + csr_off + dinv + hs scaling (R24) ----------------

__global__ __launch_bounds__(TPB) void k_passB(const int* __restrict__ staged,
                                               const int* __restrict__ gcur,
                                               int* __restrict__ csr_off,
                                               int* __restrict__ csr_src,
                                               float* __restrict__ dinv,
                                               bfu* __restrict__ hs,
                                               int n, int nbuck) {
    __shared__ int pk[BCAP];
    __shared__ int hist[256];
    __shared__ int nbase[256];
    __shared__ int cur[256];
    __shared__ int sboff[256];
    __shared__ float sdinv[256];
    __shared__ int wsum[4];
    int b = blockIdx.x;
    int t = threadIdx.x;
    int lane = t & 63, wv = t >> 6;
    int n0 = b << 8;
    int n1 = n0 + 256; if (n1 > n) n1 = n;

    hist[t] = 0; cur[t] = 0;
    int cv = (t < nbuck) ? gcur[t] : 0;
    // copy-in over full BCAP: no dependency on cnt, loads issue immediately
    for (int i = t; i < BCAP; i += TPB) pk[i] = staged[b * BCAP + i];
    int s1 = wave_iscan(cv, lane);
    if (lane == 63) wsum[wv] = s1;
    __syncthreads();   // #1
    int add1 = 0;
    if (wv > 0) add1 += wsum[0];
    if (wv > 1) add1 += wsum[1];
    if (wv > 2) add1 += wsum[2];
    sboff[t] = add1 + s1;   // inclusive prefix
    __syncthreads();   // #2
    int base = (b == 0) ? 0 : sboff[b - 1];
    int cnt = sboff[b] - base;

    for (int i = t; i < cnt; i += TPB) atomicAdd(&hist[pk[i] & 255], 1);
    __syncthreads();   // #3

    int v = hist[t];
    int s2 = wave_iscan(v, lane);
    if (lane == 63) wsum[wv] = s2;
    __syncthreads();   // #4
    int add2 = 0;
    if (wv > 0) add2 += wsum[0];
    if (wv > 1) add2 += wsum[1];
    if (wv > 2) add2 += wsum[2];
    int nb = add2 + s2 - v;
    nbase[t] = nb;
    float dv = rsqrtf((float)(v + 1));   // +1 self loop
    sdinv[t] = dv;
    if (n0 + t < n1) {
        csr_off[n0 + t] = base + nb;
        dinv[n0 + t] = dv;
    }
    if (b == nbuck - 1 && t == 0) csr_off[n] = base + cnt;
    __syncthreads();   // #5: nbase + sdinv visible

    for (int i = t; i < cnt; i += TPB) {
        int p = pk[i];
        int dloc = p & 255;
        int r = atomicAdd(&cur[dloc], 1);
        csr_src[base + nbase[dloc] + r] = p >> 8;
    }

    // scale this bucket's hs rows by dinv (gemm1 wrote unscaled xW1)
    int rows = n1 - n0;
    for (int i = t; i < rows * 8; i += TPB) {   // 8 x uint4 per 128B row
        int row = i >> 3;
        float d = sdinv[row];
        bfu* p = hs + (size_t)(n0 + row) * 64 + (i & 7) * 8;
        uint4 q = *(const uint4*)p;
        unsigned* qq = (unsigned*)&q;
        uint4 o;
        unsigned* oo = (unsigned*)&o;
#pragma unroll
        for (int j = 0; j < 4; j++) {
            float lo = blo(qq[j]) * d;
            float hi = bhi(qq[j]) * d;
            oo[j] = (unsigned)f2bf(lo) | ((unsigned)f2bf(hi) << 16);
        }
        *(uint4*)p = o;
    }
}

// ---------------- Aggregation (R19): wide row gather (dwordx4) ----------------
// Wave = 1 node. Lane map: g = lane>>3 (row slot 0..7), c = lane&7
// (8-feature chunk). One dwordx4 gather = 8 neighbor rows x 128B.
// Feature totals via 3 shfl_xor rounds once per node.
// FUSE: per-wave 64x64 W2 matmul on the relu'd row (gemm2 fusion, R16).

__device__ __forceinline__ void acc_u4(float* acc, uint4 q) {
    acc[0] += blo(q.x); acc[1] += bhi(q.x);
    acc[2] += blo(q.y); acc[3] += bhi(q.y);
    acc[4] += blo(q.z); acc[5] += bhi(q.z);
    acc[6] += blo(q.w); acc[7] += bhi(q.w);
}

template <bool FUSE>
__global__ __launch_bounds__(TPB) void k_agg(const bfu* __restrict__ hs,
                                             const int* __restrict__ csr_off,
                                             const int* __restrict__ csr_src,
                                             const float* __restrict__ dinv,
                                             const float* __restrict__ bias,
                                             const float* __restrict__ W2,
                                             bfu* __restrict__ out, int n) {
    __shared__ float rowbuf[4][64];
    int wv = threadIdx.x >> 6;
    int node = blockIdx.x * 4 + wv;
    int lane = threadIdx.x & 63;
    int g = lane >> 3;             // row slot within batch
    int c = lane & 7;              // feature chunk (feats c*8 .. c*8+7)
    if (node >= n) return;
    int p0 = csr_off[node];
    int p1 = csr_off[node + 1];
    int deg = p1 - p0;
    float d = dinv[node];          // issue early, needed late

    // self row (hot line), added once after the cross-lane reduction
    uint4 selfv = *(const uint4*)(hs + (size_t)node * 64 + c * 8);

    float acc[8];
#pragma unroll
    for (int j = 0; j < 8; j++) acc[j] = 0.f;

    for (int base = 0; base < deg; base += 16) {
        int rem = deg - base;
        int li0 = p0 + base + g;
        if (rem > 8) {
            int li1 = li0 + 8;
            int idx0 = csr_src[li0];
            int idx1 = csr_src[li1 < p1 ? li1 : p0];
            bool v1 = (8 + g) < rem;
            uint4 q0 = *(const uint4*)(hs + (size_t)idx0 * 64 + c * 8);
            uint4 q1 = *(const uint4*)(hs + (size_t)(v1 ? idx1 : node) * 64 + c * 8);
            if (!v1) q1 = make_uint4(0u, 0u, 0u, 0u);
            acc_u4(acc, q0);
            acc_u4(acc, q1);
        } else {
            bool v0 = g < rem;
            int idx0 = csr_src[li0 < p1 ? li0 : p0];
            uint4 q0 = *(const uint4*)(hs + (size_t)(v0 ? idx0 : node) * 64 + c * 8);
            if (!v0) q0 = make_uint4(0u, 0u, 0u, 0u);
            acc_u4(acc, q0);
        }
    }

    // reduce across row-slot groups (lane bits 3,4,5)
#pragma unroll
    for (int j = 0; j < 8; j++) {
        acc[j] += __shfl_xor(acc[j], 8);
        acc[j] += __shfl_xor(acc[j], 16);
        acc[j] += __shfl_xor(acc[j], 32);
    }
    // self loop (each lane keeps a consistent replicated copy)
    acc_u4(acc, selfv);

    float4 b0 = *(const float4*)&bias[c * 8];
    float4 b1 = *(const float4*)&bias[c * 8 + 4];
    float v[8];
    v[0] = fmaxf(d * acc[0] + b0.x, 0.f);
    v[1] = fmaxf(d * acc[1] + b0.y, 0.f);
    v[2] = fmaxf(d * acc[2] + b0.z, 0.f);
    v[3] = fmaxf(d * acc[3] + b0.w, 0.f);
    v[4] = fmaxf(d * acc[4] + b1.x, 0.f);
    v[5] = fmaxf(d * acc[5] + b1.y, 0.f);
    v[6] = fmaxf(d * acc[6] + b1.z, 0.f);
    v[7] = fmaxf(d * acc[7] + b1.w, 0.f);

    if (!FUSE) {
        if (g == 0) {   // lanes 0..7 write the 128B row
            uint4 o;
            o.x = (unsigned)f2bf(v[0]) | ((unsigned)f2bf(v[1]) << 16);
            o.y = (unsigned)f2bf(v[2]) | ((unsigned)f2bf(v[3]) << 16);
            o.z = (unsigned)f2bf(v[4]) | ((unsigned)f2bf(v[5]) << 16);
            o.w = (unsigned)f2bf(v[6]) | ((unsigned)f2bf(v[7]) << 16);
            *(uint4*)(out + (size_t)node * 64 + c * 8) = o;
        }
    } else {
        // fused gemm2: out[node][lane] = f2bf(d * sum_k row[k] * W2[k][lane])
        if (g == 0) {
            *(float4*)&rowbuf[wv][c * 8]     = make_float4(v[0], v[1], v[2], v[3]);
            *(float4*)&rowbuf[wv][c * 8 + 4] = make_float4(v[4], v[5], v[6], v[7]);
        }
        __builtin_amdgcn_wave_barrier();   // ds_write before ds_read (same wave: HW in-order)
        float a = 0.f;
#pragma unroll 16
        for (int k = 0; k < 64; k++) a += rowbuf[wv][k] * W2[k * 64 + lane];
        out[(size_t)node * 64 + lane] = f2bf(d * a);
    }
}

// ---------------- Pool: sorted batch; uniform-chunk fast path (bf16 reads) ----------------

__global__ __launch_bounds__(TPB) void k_pool(const bfu* __restrict__ h,
                                              const int* __restrict__ batch, int n,
                                              float* __restrict__ gsum,
                                              int* __restrict__ gcnt) {
    const int CH = 16;
    int wid = blockIdx.x * 4 + (threadIdx.x >> 6);
    int lane = threadIdx.x & 63;
    int i0 = wid * CH;
    if (i0 >= n) return;
    int i1 = i0 + CH; if (i1 > n) i1 = n;
    int g0 = batch[i0];
    int g1 = batch[i1 - 1];
    if (g0 == g1) {
        float acc = 0.f;
#pragma unroll
        for (int i = 0; i < CH; i++) {
            int idx = i0 + i;
            if (idx < i1) acc += bf2f(h[(size_t)idx * 64 + lane]);
        }
        atomicAdd(&gsum[g0 * 64 + lane], acc);
        if (lane == 0) atomicAdd(&gcnt[g0], i1 - i0);
    } else {
        int cur = g0;
        float acc = 0.f;
        int cnt = 0;
        for (int i = i0; i < i1; i++) {
            int g = batch[i];
            if (g != cur) {
                atomicAdd(&gsum[cur * 64 + lane], acc);
                if (lane == 0) atomicAdd(&gcnt[cur], cnt);
                acc = 0.f; cnt = 0; cur = g;
            }
            acc += bf2f(h[(size_t)i * 64 + lane]);
            cnt++;
        }
        atomicAdd(&gsum[cur * 64 + lane], acc);
        if (lane == 0) atomicAdd(&gcnt[cur], cnt);
    }
}

// ---------------- Head, stage 1 ----------------

__global__ __launch_bounds__(TPB) void k_head1(const float* __restrict__ gsum,
                                               const int* __restrict__ gcnt,
                                               const float* __restrict__ fc1w,
                                               const float* __restrict__ fc1b,
                                               float* __restrict__ z) {
    int t = threadIdx.x;
    int g = blockIdx.x * 2 + (t >> 7);
    int o = t & 127;
    int c = gcnt[g]; if (c < 1) c = 1;
    float inv = 1.0f / (float)c;
    float a = fc1b[o];
#pragma unroll 16
    for (int j = 0; j < 64; j++) {
        float pj = gsum[g * 64 + j] * inv;
        a += pj * fc1w[j * 128 + o];
    }
    z[g * 128 + o] = fmaxf(a, 0.f);
}

// ---------------- Head, stage 2 ----------------

__global__ __launch_bounds__(TPB) void k_head2(const float* __restrict__ z,
                                               const float* __restrict__ fc2w,
                                               const float* __restrict__ fc2b,
                                               float* __restrict__ out) {
    int t = threadIdx.x;
    int g = t >> 2, c = t & 3;
    float a = fc2b[c];
#pragma unroll 16
    for (int o = 0; o < 128; o++) a += z[g * 128 + o] * fc2w[o * 4 + c];
    out[t] = a;
}

// ---------------- launch ----------------

extern "C" void kernel_launch(void* const* d_in, const int* in_sizes, int n_in,
                              void* d_out, int out_size, void* d_ws, size_t ws_size,
                              hipStream_t stream) {
    const float* x    = (const float*)d_in[0];
    const int*   ei   = (const int*)d_in[1];
    const int*   batch= (const int*)d_in[2];
    const float* W1   = (const float*)d_in[3];
    const float* b1   = (const float*)d_in[4];
    const float* W2   = (const float*)d_in[5];
    const float* b2   = (const float*)d_in[6];
    const float* fc1w = (const float*)d_in[7];
    const float* fc1b = (const float*)d_in[8];
    const float* fc2w = (const float*)d_in[9];
    const float* fc2b = (const float*)d_in[10];

    const int n = in_sizes[2];        // 50000
    const int E = in_sizes[1] / 2;    // 800000
    const int* srcv = ei;
    const int* dstv = ei + E;
    const int nbuck = (n + 255) >> 8; // 196 (must be <= 256)

    // workspace carve; zeroed region contiguous at front
    char* w = (char*)d_ws;
    int*   gcur   = (int*)w;            w += 256 * 4;
    int*   gcnt   = (int*)w;            w += 64 * 4;
    float* gsum   = (float*)w;          w += 64 * 64 * 4;
    size_t zbytes = (size_t)w - (size_t)d_ws;
    int*   csr_off= (int*)w;            w += (size_t)(n + 1) * 4;
    float* dinv   = (float*)w;          w += (size_t)n * 4;
    int*   csr_src= (int*)w;            w += (size_t)E * 4;
    int*   staged = (int*)w;            w += (size_t)nbuck * BCAP * 4;
    float* zbuf   = (float*)w;          w += 64 * 128 * 4;
    w = (char*)(((size_t)w + 255) & ~(size_t)255);
    bfu* hs = (bfu*)w;                  w += (size_t)n * 64 * 2;
    w = (char*)(((size_t)w + 255) & ~(size_t)255);
    bfu* hb = (bfu*)w;                  w += (size_t)n * 64 * 2;

    hipMemsetAsync(d_ws, 0, zbytes, stream);

    int gA = (E + CHUNK_A - 1) / CHUNK_A;   // 196
    int gRows = (n + 63) / 64;              // 782
    int gNode = (n + 3) / 4;

    // dispatch 1: passA (edge bucketing) || gemm1 (x*W1 -> hs, unscaled)
    k_fused1<<<gA + gRows, TPB, 0, stream>>>(srcv, dstv, E, gcur, staged, nbuck,
                                             gA, x, W1, hs, n);
    // dispatch 2: passB: CSR + dinv + scale hs rows by dinv
    k_passB<<<nbuck, TPB, 0, stream>>>(staged, gcur, csr_off, csr_src, dinv, hs,
                                       n, nbuck);
    // agg1 + fused gemm2: hs -> (agg,relu,+b1) -> *W2*dinv -> hb
    k_agg<true><<<gNode, TPB, 0, stream>>>(hs, csr_off, csr_src, dinv, b1, W2, hb, n);
    // agg2: hb -> (agg,relu,+b2) -> hs
    k_agg<false><<<gNode, TPB, 0, stream>>>(hb, csr_off, csr_src, dinv, b2, nullptr, hs, n);

    int nwaves16 = (n + 15) / 16;
    k_pool<<<(nwaves16 + 3) / 4, TPB, 0, stream>>>(hs, batch, n, gsum, gcnt);
    k_head1<<<32, TPB, 0, stream>>>(gsum, gcnt, fc1w, fc1b, zbuf);
    k_head2<<<1, TPB, 0, stream>>>(zbuf, fc2w, fc2b, (float*)d_out);
}

// Round 13
// 216.606 us; speedup vs baseline: 1.8544x; 1.0061x over previous
//
#include <hip/hip_runtime.h>
#include <hip/hip_bf16.h>

// GNN: 2x GCNConv(relu) + mean-pool + MLP head.
// Sizes fixed: N=50000, E=800000, F_IN=256, H=64, NC=4, NG=64.
//
// R9: hs/hb bf16, f32 accumulate. R11/R19: wide packed gather.
// R15: decomposition: pool+head1+head2 = 2.6us, dispatch overhead ~0;
//      harness fill (~42.5us) counts inside dur_us (settled R22).
// R16: gemm2 fused into agg1 (free) -> kept.
// R17-R19: agg converges at 42.5us, FETCH 33MB invariant (TCC wall).
// R20/R21: gemm1 pure-bf16 + barrier-free streaming.
// R22: atomic CSR build regressed; R23: shfl-scan passes (224.0).
// R24: passA || gemm1 merged dispatch; dinv scale deferred to passB
//      (217.9). Budget: fused1+passB ~86us vs ~15us floor.
// R25 (this round): f2bf codegen fix. The hand-rolled round-to-nearest
//      f2bf is 3-4 VALU ops; gemm1's A-convert does 16/lane/K-step ->
//      conversion VALU dominates the MFMA branch. Swap to
//      __float2bfloat16 (RNE, bit-identical): compiler emits
//      v_cvt_pk_bf16_f32 (2 floats/op) per guide m240. Applied via the
//      single f2bf body (gemm1, passB rescale, agg epilogues).

#define TPB 256
#define CHUNK_A 4096
#define BCAP 4608          // per-bucket staging capacity (mean 4096, +8 sigma)

typedef unsigned short bfu;
typedef __attribute__((ext_vector_type(8))) short s16x8;
typedef __attribute__((ext_vector_type(4))) float f32x4;

__device__ __forceinline__ float bf2f(bfu u) {
    union { unsigned u32; float f; } c; c.u32 = ((unsigned)u) << 16; return c.f;
}
__device__ __forceinline__ bfu f2bf(float f) {
    // RNE f32->bf16 via compiler cast: emits v_cvt_pk_bf16_f32 for pairs
    // (m240: scalar casts beat hand-written cvt; bit-identical to the old
    // manual 0x7FFF+lsb rounding).
    __hip_bfloat16 h = __float2bfloat16(f);
    union { __hip_bfloat16 b; bfu u; } c; c.b = h; return c.u;
}
__device__ __forceinline__ float blo(unsigned w) {
    union { unsigned u32; float f; } c; c.u32 = w << 16; return c.f;
}
__device__ __forceinline__ float bhi(unsigned w) {
    union { unsigned u32; float f; } c; c.u32 = w & 0xFFFF0000u; return c.f;
}

// wave-level inclusive scan (Hillis-Steele over 64 lanes, register-only)
__device__ __forceinline__ int wave_iscan(int s, int lane) {
#pragma unroll
    for (int off = 1; off < 64; off <<= 1) {
        int u = __shfl_up(s, off);
        if (lane >= off) s += u;
    }
    return s;
}

__device__ __forceinline__ int swzW(int c, int k) {
    return c * 256 + (k ^ ((c & 15) << 3));
}

// ---------------- fused dispatch 1: passA (blocks < gA) || gemm1 (rest) ----------------
// passA: chunked bucket staging (R23 de-serialized). packed edge:
//   (src<<8)|(dst&255); requires n <= 65536, nbuck <= 256.
// gemm1: barrier-free streaming bf16 MFMA, UNSCALED output (dinv applied
//   later in passB). W staged once to 32KB LDS ([c][k], XOR swizzle);
//   A fragments straight from global; C/D map col=lane&15,
//   row=(lane>>4)*4+reg (m89-verified).
// LDS union: passA uses 24.6KB inside gemm1's 32KB Bh region.

__global__ __launch_bounds__(TPB) void k_fused1(const int* __restrict__ srcv,
                                                const int* __restrict__ dstv, int E,
                                                int* __restrict__ gcur,
                                                int* __restrict__ staged, int nbuck,
                                                int gA,
                                                const float* __restrict__ A,
                                                const float* __restrict__ W,
                                                bfu* __restrict__ C, int n) {
    __shared__ __align__(16) char smem[32768];
    int t = threadIdx.x;
    int lane = t & 63, wv = t >> 6;

    if ((int)blockIdx.x < gA) {
        // ================= passA =================
        int* pk = (int*)smem;                                  // 16384 B
        unsigned char* bktl = (unsigned char*)(smem + 16384);  //  4096 B
        int* hist  = (int*)(smem + 20480);                     //  1024 B
        int* ebase = (int*)(smem + 21504);
        int* gbase = (int*)(smem + 22528);
        int* lcur  = (int*)(smem + 23552);
        int* wsum  = (int*)(smem + 24576);                     //    16 B
        int e0 = blockIdx.x * CHUNK_A;
        int e1 = e0 + CHUNK_A; if (e1 > E) e1 = E;
        int cblk = e1 - e0;

        hist[t] = 0; lcur[t] = 0;
        __syncthreads();

        int myd[16], mys[16];
#pragma unroll
        for (int q = 0; q < 16; q++) {
            int i = e0 + t + q * TPB;
            myd[q] = (i < e1) ? dstv[i] : -1;
        }
#pragma unroll
        for (int q = 0; q < 16; q++) {
            int i = e0 + t + q * TPB;
            mys[q] = (i < e1) ? srcv[i] : 0;
        }
#pragma unroll
        for (int q = 0; q < 16; q++)
            if (myd[q] >= 0) atomicAdd(&hist[myd[q] >> 8], 1);
        __syncthreads();

        int v = hist[t];
        int s = wave_iscan(v, lane);
        if (lane == 63) wsum[wv] = s;
        __syncthreads();
        int add = 0;
        if (wv > 0) add += wsum[0];
        if (wv > 1) add += wsum[1];
        if (wv > 2) add += wsum[2];
        int eb = add + s - v;
        ebase[t] = eb;
        if (t < nbuck && v > 0) gbase[t] = t * BCAP + atomicAdd(&gcur[t], v);
        __syncthreads();

#pragma unroll
        for (int q = 0; q < 16; q++) {
            int d = myd[q];
            if (d >= 0) {
                int b = d >> 8;
                int r = atomicAdd(&lcur[b], 1);
                int p = ebase[b] + r;
                pk[p] = (mys[q] << 8) | (d & 255);
                bktl[p] = (unsigned char)b;
            }
        }
        __syncthreads();

        for (int i = t; i < cblk; i += TPB) {
            int b = bktl[i];
            staged[gbase[b] + (i - ebase[b])] = pk[i];
        }
    } else {
        // ================= gemm1 (unscaled) =================
        const int K = 256;
        ushort* Bh = (ushort*)smem;    // 32 KB
        const int rbase = ((int)blockIdx.x - gA) * 64;

        {   // stage W once: col c = t&63, k-range (t>>6)*64
            int c = t & 63;
            int kg = (t >> 6) << 6;
#pragma unroll
            for (int q = 0; q < 8; q++) {
                int k8 = kg + q * 8;
                ushort4 h0, h1;
#pragma unroll
                for (int j = 0; j < 4; j++) ((bfu*)&h0)[j] = f2bf(W[(size_t)(k8 + j) * 64 + c]);
#pragma unroll
                for (int j = 0; j < 4; j++) ((bfu*)&h1)[j] = f2bf(W[(size_t)(k8 + 4 + j) * 64 + c]);
                *(ushort4*)&Bh[swzW(c, k8)]     = h0;
                *(ushort4*)&Bh[swzW(c, k8) + 4] = h1;
            }
        }
        __syncthreads();   // only barrier in this branch

        const int rl = lane & 15;
        const int kg8 = (lane >> 4) << 3;
        int r0 = rbase + wv * 16 + rl;
        const float* arow = A + (size_t)(r0 < n ? r0 : (n - 1)) * K;

        f32x4 acc[4];
#pragma unroll
        for (int j = 0; j < 4; j++) acc[j] = {0.f, 0.f, 0.f, 0.f};

#pragma unroll
        for (int ks = 0; ks < 8; ks++) {
            int k0 = ks * 32 + kg8;
            float4 xa = *(const float4*)(arow + k0);
            float4 xb = *(const float4*)(arow + k0 + 4);
            s16x8 af;
            ((bfu*)&af)[0] = f2bf(xa.x);
            ((bfu*)&af)[1] = f2bf(xa.y);
            ((bfu*)&af)[2] = f2bf(xa.z);
            ((bfu*)&af)[3] = f2bf(xa.w);
            ((bfu*)&af)[4] = f2bf(xb.x);
            ((bfu*)&af)[5] = f2bf(xb.y);
            ((bfu*)&af)[6] = f2bf(xb.z);
            ((bfu*)&af)[7] = f2bf(xb.w);
#pragma unroll
            for (int ct = 0; ct < 4; ct++) {
                s16x8 bf = *(const s16x8*)&Bh[swzW(ct * 16 + rl, k0)];
                acc[ct] = __builtin_amdgcn_mfma_f32_16x16x32_bf16(af, bf, acc[ct], 0, 0, 0);
            }
        }

        const int rq = (lane >> 4) << 2;
#pragma unroll
        for (int reg = 0; reg < 4; reg++) {
            int r = rbase + wv * 16 + rq + reg;
            if (r < n) {
#pragma unroll
                for (int ct = 0; ct < 4; ct++) {
                    C[(size_t)r * 64 + ct * 16 + rl] = f2bf(acc[ct][reg]);
                }
            }
        }
    }
}

// ---------------- pass B: node sort + csr_off + dinv + hs scaling (R24) ----------------

__global__ __launch_bounds__(TPB) void k_passB(const int* __restrict__ staged,
                                               const int* __restrict__ gcur,
                                               int* __restrict__ csr_off,
                                               int* __restrict__ csr_src,
                                               float* __restrict__ dinv,
                                               bfu* __restrict__ hs,
                                               int n, int nbuck) {
    __shared__ int pk[BCAP];
    __shared__ int hist[256];
    __shared__ int nbase[256];
    __shared__ int cur[256];
    __shared__ int sboff[256];
    __shared__ float sdinv[256];
    __shared__ int wsum[4];
    int b = blockIdx.x;
    int t = threadIdx.x;
    int lane = t & 63, wv = t >> 6;
    int n0 = b << 8;
    int n1 = n0 + 256; if (n1 > n) n1 = n;

    hist[t] = 0; cur[t] = 0;
    int cv = (t < nbuck) ? gcur[t] : 0;
    // copy-in over full BCAP: no dependency on cnt, loads issue immediately
    for (int i = t; i < BCAP; i += TPB) pk[i] = staged[b * BCAP + i];
    int s1 = wave_iscan(cv, lane);
    if (lane == 63) wsum[wv] = s1;
    __syncthreads();   // #1
    int add1 = 0;
    if (wv > 0) add1 += wsum[0];
    if (wv > 1) add1 += wsum[1];
    if (wv > 2) add1 += wsum[2];
    sboff[t] = add1 + s1;   // inclusive prefix
    __syncthreads();   // #2
    int base = (b == 0) ? 0 : sboff[b - 1];
    int cnt = sboff[b] - base;

    for (int i = t; i < cnt; i += TPB) atomicAdd(&hist[pk[i] & 255], 1);
    __syncthreads();   // #3

    int v = hist[t];
    int s2 = wave_iscan(v, lane);
    if (lane == 63) wsum[wv] = s2;
    __syncthreads();   // #4
    int add2 = 0;
    if (wv > 0) add2 += wsum[0];
    if (wv > 1) add2 += wsum[1];
    if (wv > 2) add2 += wsum[2];
    int nb = add2 + s2 - v;
    nbase[t] = nb;
    float dv = rsqrtf((float)(v + 1));   // +1 self loop
    sdinv[t] = dv;
    if (n0 + t < n1) {
        csr_off[n0 + t] = base + nb;
        dinv[n0 + t] = dv;
    }
    if (b == nbuck - 1 && t == 0) csr_off[n] = base + cnt;
    __syncthreads();   // #5: nbase + sdinv visible

    for (int i = t; i < cnt; i += TPB) {
        int p = pk[i];
        int dloc = p & 255;
        int r = atomicAdd(&cur[dloc], 1);
        csr_src[base + nbase[dloc] + r] = p >> 8;
    }

    // scale this bucket's hs rows by dinv (gemm1 wrote unscaled xW1)
    int rows = n1 - n0;
    for (int i = t; i < rows * 8; i += TPB) {   // 8 x uint4 per 128B row
        int row = i >> 3;
        float d = sdinv[row];
        bfu* p = hs + (size_t)(n0 + row) * 64 + (i & 7) * 8;
        uint4 q = *(const uint4*)p;
        unsigned* qq = (unsigned*)&q;
        uint4 o;
        unsigned* oo = (unsigned*)&o;
#pragma unroll
        for (int j = 0; j < 4; j++) {
            float lo = blo(qq[j]) * d;
            float hi = bhi(qq[j]) * d;
            oo[j] = (unsigned)f2bf(lo) | ((unsigned)f2bf(hi) << 16);
        }
        *(uint4*)p = o;
    }
}

// ---------------- Aggregation (R19): wide row gather (dwordx4) ----------------
// Wave = 1 node. Lane map: g = lane>>3 (row slot 0..7), c = lane&7
// (8-feature chunk). One dwordx4 gather = 8 neighbor rows x 128B.
// Feature totals via 3 shfl_xor rounds once per node.
// FUSE: per-wave 64x64 W2 matmul on the relu'd row (gemm2 fusion, R16).

__device__ __forceinline__ void acc_u4(float* acc, uint4 q) {
    acc[0] += blo(q.x); acc[1] += bhi(q.x);
    acc[2] += blo(q.y); acc[3] += bhi(q.y);
    acc[4] += blo(q.z); acc[5] += bhi(q.z);
    acc[6] += blo(q.w); acc[7] += bhi(q.w);
}

template <bool FUSE>
__global__ __launch_bounds__(TPB) void k_agg(const bfu* __restrict__ hs,
                                             const int* __restrict__ csr_off,
                                             const int* __restrict__ csr_src,
                                             const float* __restrict__ dinv,
                                             const float* __restrict__ bias,
                                             const float* __restrict__ W2,
                                             bfu* __restrict__ out, int n) {
    __shared__ float rowbuf[4][64];
    int wv = threadIdx.x >> 6;
    int node = blockIdx.x * 4 + wv;
    int lane = threadIdx.x & 63;
    int g = lane >> 3;             // row slot within batch
    int c = lane & 7;              // feature chunk (feats c*8 .. c*8+7)
    if (node >= n) return;
    int p0 = csr_off[node];
    int p1 = csr_off[node + 1];
    int deg = p1 - p0;
    float d = dinv[node];          // issue early, needed late

    // self row (hot line), added once after the cross-lane reduction
    uint4 selfv = *(const uint4*)(hs + (size_t)node * 64 + c * 8);

    float acc[8];
#pragma unroll
    for (int j = 0; j < 8; j++) acc[j] = 0.f;

    for (int base = 0; base < deg; base += 16) {
        int rem = deg - base;
        int li0 = p0 + base + g;
        if (rem > 8) {
            int li1 = li0 + 8;
            int idx0 = csr_src[li0];
            int idx1 = csr_src[li1 < p1 ? li1 : p0];
            bool v1 = (8 + g) < rem;
            uint4 q0 = *(const uint4*)(hs + (size_t)idx0 * 64 + c * 8);
            uint4 q1 = *(const uint4*)(hs + (size_t)(v1 ? idx1 : node) * 64 + c * 8);
            if (!v1) q1 = make_uint4(0u, 0u, 0u, 0u);
            acc_u4(acc, q0);
            acc_u4(acc, q1);
        } else {
            bool v0 = g < rem;
            int idx0 = csr_src[li0 < p1 ? li0 : p0];
            uint4 q0 = *(const uint4*)(hs + (size_t)(v0 ? idx0 : node) * 64 + c * 8);
            if (!v0) q0 = make_uint4(0u, 0u, 0u, 0u);
            acc_u4(acc, q0);
        }
    }

    // reduce across row-slot groups (lane bits 3,4,5)
#pragma unroll
    for (int j = 0; j < 8; j++) {
        acc[j] += __shfl_xor(acc[j], 8);
        acc[j] += __shfl_xor(acc[j], 16);
        acc[j] += __shfl_xor(acc[j], 32);
    }
    // self loop (each lane keeps a consistent replicated copy)
    acc_u4(acc, selfv);

    float4 b0 = *(const float4*)&bias[c * 8];
    float4 b1 = *(const float4*)&bias[c * 8 + 4];
    float v[8];
    v[0] = fmaxf(d * acc[0] + b0.x, 0.f);
    v[1] = fmaxf(d * acc[1] + b0.y, 0.f);
    v[2] = fmaxf(d * acc[2] + b0.z, 0.f);
    v[3] = fmaxf(d * acc[3] + b0.w, 0.f);
    v[4] = fmaxf(d * acc[4] + b1.x, 0.f);
    v[5] = fmaxf(d * acc[5] + b1.y, 0.f);
    v[6] = fmaxf(d * acc[6] + b1.z, 0.f);
    v[7] = fmaxf(d * acc[7] + b1.w, 0.f);

    if (!FUSE) {
        if (g == 0) {   // lanes 0..7 write the 128B row
            uint4 o;
            o.x = (unsigned)f2bf(v[0]) | ((unsigned)f2bf(v[1]) << 16);
            o.y = (unsigned)f2bf(v[2]) | ((unsigned)f2bf(v[3]) << 16);
            o.z = (unsigned)f2bf(v[4]) | ((unsigned)f2bf(v[5]) << 16);
            o.w = (unsigned)f2bf(v[6]) | ((unsigned)f2bf(v[7]) << 16);
            *(uint4*)(out + (size_t)node * 64 + c * 8) = o;
        }
    } else {
        // fused gemm2: out[node][lane] = f2bf(d * sum_k row[k] * W2[k][lane])
        if (g == 0) {
            *(float4*)&rowbuf[wv][c * 8]     = make_float4(v[0], v[1], v[2], v[3]);
            *(float4*)&rowbuf[wv][c * 8 + 4] = make_float4(v[4], v[5], v[6], v[7]);
        }
        __builtin_amdgcn_wave_barrier();   // ds_write before ds_read (same wave: HW in-order)
        float a = 0.f;
#pragma unroll 16
        for (int k = 0; k < 64; k++) a += rowbuf[wv][k] * W2[k * 64 + lane];
        out[(size_t)node * 64 + lane] = f2bf(d * a);
    }
}

// ---------------- Pool: sorted batch; uniform-chunk fast path (bf16 reads) ----------------

__global__ __launch_bounds__(TPB) void k_pool(const bfu* __restrict__ h,
                                              const int* __restrict__ batch, int n,
                                              float* __restrict__ gsum,
                                              int* __restrict__ gcnt) {
    const int CH = 16;
    int wid = blockIdx.x * 4 + (threadIdx.x >> 6);
    int lane = threadIdx.x & 63;
    int i0 = wid * CH;
    if (i0 >= n) return;
    int i1 = i0 + CH; if (i1 > n) i1 = n;
    int g0 = batch[i0];
    int g1 = batch[i1 - 1];
    if (g0 == g1) {
        float acc = 0.f;
#pragma unroll
        for (int i = 0; i < CH; i++) {
            int idx = i0 + i;
            if (idx < i1) acc += bf2f(h[(size_t)idx * 64 + lane]);
        }
        atomicAdd(&gsum[g0 * 64 + lane], acc);
        if (lane == 0) atomicAdd(&gcnt[g0], i1 - i0);
    } else {
        int cur = g0;
        float acc = 0.f;
        int cnt = 0;
        for (int i = i0; i < i1; i++) {
            int g = batch[i];
            if (g != cur) {
                atomicAdd(&gsum[cur * 64 + lane], acc);
                if (lane == 0) atomicAdd(&gcnt[cur], cnt);
                acc = 0.f; cnt = 0; cur = g;
            }
            acc += bf2f(h[(size_t)i * 64 + lane]);
            cnt++;
        }
        atomicAdd(&gsum[cur * 64 + lane], acc);
        if (lane == 0) atomicAdd(&gcnt[cur], cnt);
    }
}

// ---------------- Head, stage 1 ----------------

__global__ __launch_bounds__(TPB) void k_head1(const float* __restrict__ gsum,
                                               const int* __restrict__ gcnt,
                                               const float* __restrict__ fc1w,
                                               const float* __restrict__ fc1b,
                                               float* __restrict__ z) {
    int t = threadIdx.x;
    int g = blockIdx.x * 2 + (t >> 7);
    int o = t & 127;
    int c = gcnt[g]; if (c < 1) c = 1;
    float inv = 1.0f / (float)c;
    float a = fc1b[o];
#pragma unroll 16
    for (int j = 0; j < 64; j++) {
        float pj = gsum[g * 64 + j] * inv;
        a += pj * fc1w[j * 128 + o];
    }
    z[g * 128 + o] = fmaxf(a, 0.f);
}

// ---------------- Head, stage 2 ----------------

__global__ __launch_bounds__(TPB) void k_head2(const float* __restrict__ z,
                                               const float* __restrict__ fc2w,
                                               const float* __restrict__ fc2b,
                                               float* __restrict__ out) {
    int t = threadIdx.x;
    int g = t >> 2, c = t & 3;
    float a = fc2b[c];
#pragma unroll 16
    for (int o = 0; o < 128; o++) a += z[g * 128 + o] * fc2w[o * 4 + c];
    out[t] = a;
}

// ---------------- launch ----------------

extern "C" void kernel_launch(void* const* d_in, const int* in_sizes, int n_in,
                              void* d_out, int out_size, void* d_ws, size_t ws_size,
                              hipStream_t stream) {
    const float* x    = (const float*)d_in[0];
    const int*   ei   = (const int*)d_in[1];
    const int*   batch= (const int*)d_in[2];
    const float* W1   = (const float*)d_in[3];
    const float* b1   = (const float*)d_in[4];
    const float* W2   = (const float*)d_in[5];
    const float* b2   = (const float*)d_in[6];
    const float* fc1w = (const float*)d_in[7];
    const float* fc1b = (const float*)d_in[8];
    const float* fc2w = (const float*)d_in[9];
    const float* fc2b = (const float*)d_in[10];

    const int n = in_sizes[2];        // 50000
    const int E = in_sizes[1] / 2;    // 800000
    const int* srcv = ei;
    const int* dstv = ei + E;
    const int nbuck = (n + 255) >> 8; // 196 (must be <= 256)

    // workspace carve; zeroed region contiguous at front
    char* w = (char*)d_ws;
    int*   gcur   = (int*)w;            w += 256 * 4;
    int*   gcnt   = (int*)w;            w += 64 * 4;
    float* gsum   = (float*)w;          w += 64 * 64 * 4;
    size_t zbytes = (size_t)w - (size_t)d_ws;
    int*   csr_off= (int*)w;            w += (size_t)(n + 1) * 4;
    float* dinv   = (float*)w;          w += (size_t)n * 4;
    int*   csr_src= (int*)w;            w += (size_t)E * 4;
    int*   staged = (int*)w;            w += (size_t)nbuck * BCAP * 4;
    float* zbuf   = (float*)w;          w += 64 * 128 * 4;
    w = (char*)(((size_t)w + 255) & ~(size_t)255);
    bfu* hs = (bfu*)w;                  w += (size_t)n * 64 * 2;
    w = (char*)(((size_t)w + 255) & ~(size_t)255);
    bfu* hb = (bfu*)w;                  w += (size_t)n * 64 * 2;

    hipMemsetAsync(d_ws, 0, zbytes, stream);

    int gA = (E + CHUNK_A - 1) / CHUNK_A;   // 196
    int gRows = (n + 63) / 64;              // 782
    int gNode = (n + 3) / 4;

    // dispatch 1: passA (edge bucketing) || gemm1 (x*W1 -> hs, unscaled)
    k_fused1<<<gA + gRows, TPB, 0, stream>>>(srcv, dstv, E, gcur, staged, nbuck,
                                             gA, x, W1, hs, n);
    // dispatch 2: passB: CSR + dinv + scale hs rows by dinv
    k_passB<<<nbuck, TPB, 0, stream>>>(staged, gcur, csr_off, csr_src, dinv, hs,
                                       n, nbuck);
    // agg1 + fused gemm2: hs -> (agg,relu,+b1) -> *W2*dinv -> hb
    k_agg<true><<<gNode, TPB, 0, stream>>>(hs, csr_off, csr_src, dinv, b1, W2, hb, n);
    // agg2: hb -> (agg,relu,+b2) -> hs
    k_agg<false><<<gNode, TPB, 0, stream>>>(hb, csr_off, csr_src, dinv, b2, nullptr, hs, n);

    int nwaves16 = (n + 15) / 16;
    k_pool<<<(nwaves16 + 3) / 4, TPB, 0, stream>>>(hs, batch, n, gsum, gcnt);
    k_head1<<<32, TPB, 0, stream>>>(gsum, gcnt, fc1w, fc1b, zbuf);
    k_head2<<<1, TPB, 0, stream>>>(zbuf, fc2w, fc2b, (float*)d_out);
}